// Round 1
// baseline (1473.885 us; speedup 1.0000x reference)
//
#include <hip/hip_runtime.h>

// ---------------------------------------------------------------------------
// DeepseekV4Compressor on MI355X (gfx950)
//
// Strategy: fp32 GEMM emulated via split-bf16 (hi/lo) MFMA, K' = 3*K:
//   seg0: A_hi * W_hi, seg1: A_lo * W_hi, seg2: A_hi * W_lo  (lo*lo dropped)
// GEMM: m97-verified structure: 128x128 tile, BK=64, 4 waves,
// global_load_lds width=16, single LDS buffer, 2 barriers / k-step.
// Per-batch X staging keeps workspace at 128 MiB.
// ---------------------------------------------------------------------------

typedef __attribute__((ext_vector_type(8))) __bf16 bf16x8;
typedef __attribute__((ext_vector_type(4))) float f32x4;

__device__ __forceinline__ void gld16(const void* g, void* l) {
    __builtin_amdgcn_global_load_lds(
        (const __attribute__((address_space(1))) void*)g,
        (__attribute__((address_space(3))) void*)l,
        16, 0, 0);
}

__device__ __forceinline__ unsigned short bf16rn(float f) {
    unsigned int u = __float_as_uint(f);
    u += 0x7FFF + ((u >> 16) & 1);   // round-to-nearest-even
    return (unsigned short)(u >> 16);
}
__device__ __forceinline__ float bf16tof(unsigned short h) {
    return __uint_as_float(((unsigned int)h) << 16);
}

// ---- convert x (one batch: 4096x4096 f32) into hi/lo bf16 -----------------
__global__ void convert_x_kernel(const float4* __restrict__ src,
                                 ushort4* __restrict__ hi,
                                 ushort4* __restrict__ lo) {
    const int i = blockIdx.x * 256 + threadIdx.x;   // 4,194,304 float4s
    const float4 v = src[i];
    ushort4 h, l;
    h.x = bf16rn(v.x); l.x = bf16rn(v.x - bf16tof(h.x));
    h.y = bf16rn(v.y); l.y = bf16rn(v.y - bf16tof(h.y));
    h.z = bf16rn(v.z); l.z = bf16rn(v.z - bf16tof(h.z));
    h.w = bf16rn(v.w); l.w = bf16rn(v.w - bf16tof(h.w));
    hi[i] = h; lo[i] = l;
}

// ---- convert W_kv (1024x4096) ++ W_gate (1024x4096) -> W' (2048x4096) -----
__global__ void convert_w_kernel(const float* __restrict__ Wkv,
                                 const float* __restrict__ Wgate,
                                 ushort4* __restrict__ hi,
                                 ushort4* __restrict__ lo) {
    const int i = blockIdx.x * 256 + threadIdx.x;   // 2,097,152 float4s
    const size_t e = (size_t)i * 4;
    const int row = (int)(e >> 12);
    const int col = (int)(e & 4095);
    const float* srcrow = (row < 1024) ? (Wkv + ((size_t)row << 12))
                                       : (Wgate + ((size_t)(row - 1024) << 12));
    const float4 v = *(const float4*)(srcrow + col);
    ushort4 h, l;
    h.x = bf16rn(v.x); l.x = bf16rn(v.x - bf16tof(h.x));
    h.y = bf16rn(v.y); l.y = bf16rn(v.y - bf16tof(h.y));
    h.z = bf16rn(v.z); l.z = bf16rn(v.z - bf16tof(h.z));
    h.w = bf16rn(v.w); l.w = bf16rn(v.w - bf16tof(h.w));
    hi[i] = h; lo[i] = l;
}

// ---- softmax of ape: w8 = softmax over 8 rows, w0 = softmax over first 4 --
__global__ void softmax_kernel(const float* __restrict__ ape,
                               float* __restrict__ w8,
                               float* __restrict__ w0) {
    const int d = threadIdx.x;   // 512 threads
    float v[8];
#pragma unroll
    for (int r = 0; r < 4; ++r) v[r] = ape[r * 1024 + d];
#pragma unroll
    for (int r = 0; r < 4; ++r) v[4 + r] = ape[r * 1024 + 512 + d];
    float mx = v[0];
#pragma unroll
    for (int i = 1; i < 8; ++i) mx = fmaxf(mx, v[i]);
    float e[8], s = 0.f;
#pragma unroll
    for (int i = 0; i < 8; ++i) { e[i] = expf(v[i] - mx); s += e[i]; }
    const float inv = 1.f / s;
#pragma unroll
    for (int i = 0; i < 8; ++i) w8[i * 512 + d] = e[i] * inv;

    float mx4 = fmaxf(fmaxf(v[0], v[1]), fmaxf(v[2], v[3]));
    float e4[4], s4 = 0.f;
#pragma unroll
    for (int i = 0; i < 4; ++i) { e4[i] = expf(v[i] - mx4); s4 += e4[i]; }
    const float inv4 = 1.f / s4;
#pragma unroll
    for (int i = 0; i < 4; ++i) w0[i * 512 + d] = e4[i] * inv4;
}

// ---- split-bf16 GEMM: C[4096][2048] = A'[4096][12288] * B'[2048][12288]^T -
__global__ __launch_bounds__(256, 2) void gemm_split_kernel(
    const unsigned short* __restrict__ Xhi, const unsigned short* __restrict__ Xlo,
    const unsigned short* __restrict__ Whi, const unsigned short* __restrict__ Wlo,
    float* __restrict__ C) {
    __shared__ unsigned short sA[128 * 64];   // 16 KB
    __shared__ unsigned short sB[128 * 64];   // 16 KB

    const int t = threadIdx.x;
    const int lane = t & 63;
    const int w = t >> 6;                 // wave 0..3
    const int bn = blockIdx.x;            // 0..15  (n tile)
    const int bm = blockIdx.y;            // 0..31  (m tile)
    const int wm = (w >> 1) * 64;         // wave's 64x64 sub-tile
    const int wn = (w & 1) * 64;

    f32x4 acc[4][4];
    const f32x4 zero = {0.f, 0.f, 0.f, 0.f};
#pragma unroll
    for (int m = 0; m < 4; ++m)
#pragma unroll
        for (int n = 0; n < 4; ++n) acc[m][n] = zero;

    // staging coords: thread covers 16B; wave covers 8 rows of 128B (BK=64 bf16)
    const int srow = t >> 3;              // 0..31
    const int scol = (t & 7) * 8;         // element col (8 bf16 = 16 B)
    const size_t aoff = (size_t)(bm * 128 + srow) * 4096 + scol;
    const size_t boff = (size_t)(bn * 128 + srow) * 4096 + scol;
    unsigned short* sAdst = &sA[srow * 64 + scol];
    unsigned short* sBdst = &sB[srow * 64 + scol];

    // fragment read coords (16x16x32 bf16 layout: row=lane&15, k=(lane>>4)*8)
    const int ar = lane & 15;
    const int kb0 = (lane >> 4) * 8;
    const unsigned short* aP = &sA[(wm + ar) * 64 + kb0];
    const unsigned short* bP = &sB[(wn + ar) * 64 + kb0];

    for (int kt = 0; kt < 192; ++kt) {    // 3 segments x 64 tiles of BK=64
        const int seg = kt >> 6;
        const int kl = (kt & 63) * 64;
        const unsigned short* Ab = (seg == 1) ? Xlo : Xhi;
        const unsigned short* Bb = (seg == 2) ? Wlo : Whi;
        const unsigned short* Ag = Ab + aoff + kl;
        const unsigned short* Bg = Bb + boff + kl;

        __syncthreads();                  // previous compute done
#pragma unroll
        for (int r = 0; r < 4; ++r)
            gld16(Ag + (size_t)r * (32 * 4096), sAdst + r * (32 * 64));
#pragma unroll
        for (int r = 0; r < 4; ++r)
            gld16(Bg + (size_t)r * (32 * 4096), sBdst + r * (32 * 64));
        __syncthreads();                  // drains vmcnt -> LDS valid

#pragma unroll
        for (int kk = 0; kk < 2; ++kk) {
            bf16x8 a[4], b[4];
#pragma unroll
            for (int m = 0; m < 4; ++m)
                a[m] = *(const bf16x8*)(aP + m * (16 * 64) + kk * 32);
#pragma unroll
            for (int n = 0; n < 4; ++n)
                b[n] = *(const bf16x8*)(bP + n * (16 * 64) + kk * 32);
#pragma unroll
            for (int m = 0; m < 4; ++m)
#pragma unroll
                for (int n = 0; n < 4; ++n)
                    acc[m][n] = __builtin_amdgcn_mfma_f32_16x16x32_bf16(
                        a[m], b[n], acc[m][n], 0, 0, 0);
        }
    }

    // epilogue: C/D layout col=lane&15, row=(lane>>4)*4+i  (m89-verified)
    const int crow = bm * 128 + wm + (lane >> 4) * 4;
    const int ccol = bn * 128 + wn + (lane & 15);
#pragma unroll
    for (int m = 0; m < 4; ++m)
#pragma unroll
        for (int n = 0; n < 4; ++n) {
            float* cp = C + (size_t)(crow + m * 16) * 2048 + (ccol + n * 16);
#pragma unroll
            for (int i = 0; i < 4; ++i) cp[(size_t)i * 2048] = acc[m][n][i];
        }
}

// ---- in-place gating: kv[s][o] *= sigmoid(gate[s][o]) ---------------------
__global__ void gate_kernel(float* __restrict__ kvg) {
    const int i = blockIdx.x * 256 + threadIdx.x;  // 1,048,576 float4 units
    const int s = i >> 8;
    const int q = (i & 255) << 2;
    float* prow = kvg + ((size_t)s << 11);
    float4 kv = *(float4*)(prow + q);
    const float4 gt = *(const float4*)(prow + 1024 + q);
    kv.x *= 1.f / (1.f + expf(-gt.x));
    kv.y *= 1.f / (1.f + expf(-gt.y));
    kv.z *= 1.f / (1.f + expf(-gt.z));
    kv.w *= 1.f / (1.f + expf(-gt.w));
    *(float4*)(prow + q) = kv;
}

// ---- combine over r + RMSNorm + RoPE, one block per (c) -------------------
__global__ void combine_kernel(const float* __restrict__ gated,  // [4096][2048]
                               const float* __restrict__ w8,     // [8][512]
                               const float* __restrict__ w0,     // [4][512]
                               const float* __restrict__ cosb,   // [1024][32]
                               const float* __restrict__ sinb,
                               const float* __restrict__ normw,  // [512]
                               float* __restrict__ outb) {       // [1024][512]
    const int c = blockIdx.x;
    const int t = threadIdx.x;   // 256 threads, 2 d's each
    const int d = t * 2;

    const float* base = gated + (size_t)c * (4 * 2048);
    float o0 = 0.f, o1 = 0.f;
    if (c == 0) {
#pragma unroll
        for (int r = 0; r < 4; ++r) {
            const float2 mv = *(const float2*)(base + r * 2048 + d);
            o0 += mv.x * w0[r * 512 + d];
            o1 += mv.y * w0[r * 512 + d + 1];
        }
    } else {
#pragma unroll
        for (int r = 0; r < 4; ++r) {
            const float2 mv = *(const float2*)(base + r * 2048 + d);
            o0 += mv.x * w8[r * 512 + d];
            o1 += mv.y * w8[r * 512 + d + 1];
        }
        const float* pbase = base - 4 * 2048 + 512;   // ov of chunk c-1
#pragma unroll
        for (int r = 0; r < 4; ++r) {
            const float2 ov = *(const float2*)(pbase + r * 2048 + d);
            o0 += ov.x * w8[(4 + r) * 512 + d];
            o1 += ov.y * w8[(4 + r) * 512 + d + 1];
        }
    }

    // RMS over 512
    float p = o0 * o0 + o1 * o1;
#pragma unroll
    for (int off = 32; off > 0; off >>= 1) p += __shfl_down(p, off, 64);
    __shared__ float red[4];
    if ((t & 63) == 0) red[t >> 6] = p;
    __syncthreads();
    const float sc = rsqrtf((red[0] + red[1] + red[2] + red[3]) * (1.f / 512.f) + 1e-6f);
    o0 *= sc * normw[d];
    o1 *= sc * normw[d + 1];

    float2 res;
    if (d < 448) {
        res.x = o0; res.y = o1;
    } else {
        const int j = (d - 448) >> 1;
        const float cv = cosb[c * 32 + j];
        const float sv = sinb[c * 32 + j];
        res.x = o0 * cv - o1 * sv;
        res.y = o0 * sv + o1 * cv;
    }
    *(float2*)(outb + (size_t)c * 512 + d) = res;
}

// ---------------------------------------------------------------------------
extern "C" void kernel_launch(void* const* d_in, const int* in_sizes, int n_in,
                              void* d_out, int out_size, void* d_ws, size_t ws_size,
                              hipStream_t stream) {
    const float* x     = (const float*)d_in[0];   // (4, 4096, 4096)
    const float* cosp  = (const float*)d_in[1];   // (4, 1024, 32)
    const float* sinp  = (const float*)d_in[2];
    const float* Wkv   = (const float*)d_in[3];   // (1024, 4096)
    const float* Wgate = (const float*)d_in[4];   // (1024, 4096)
    const float* ape   = (const float*)d_in[5];   // (4, 1024)
    const float* normw = (const float*)d_in[6];   // (512,)
    float* outp = (float*)d_out;                  // (4, 1024, 512)

    char* wsb = (char*)d_ws;
    unsigned short* Xhi = (unsigned short*)(wsb);
    unsigned short* Xlo = (unsigned short*)(wsb + (size_t)32 * 1024 * 1024);
    unsigned short* Whi = (unsigned short*)(wsb + (size_t)64 * 1024 * 1024);
    unsigned short* Wlo = (unsigned short*)(wsb + (size_t)80 * 1024 * 1024);
    float* KVG = (float*)(wsb + (size_t)96 * 1024 * 1024);   // [4096][2048]
    float* W8  = (float*)(wsb + (size_t)128 * 1024 * 1024);
    float* W0  = (float*)(wsb + (size_t)128 * 1024 * 1024 + 16384);

    convert_w_kernel<<<8192, 256, 0, stream>>>(Wkv, Wgate, (ushort4*)Whi, (ushort4*)Wlo);
    softmax_kernel<<<1, 512, 0, stream>>>(ape, W8, W0);

    for (int b = 0; b < 4; ++b) {
        convert_x_kernel<<<16384, 256, 0, stream>>>(
            (const float4*)(x + (size_t)b * 16777216), (ushort4*)Xhi, (ushort4*)Xlo);
        gemm_split_kernel<<<dim3(16, 32), 256, 0, stream>>>(Xhi, Xlo, Whi, Wlo, KVG);
        gate_kernel<<<4096, 256, 0, stream>>>(KVG);
        combine_kernel<<<1024, 256, 0, stream>>>(
            KVG, W8, W0,
            cosp + (size_t)b * 32768, sinp + (size_t)b * 32768,
            normw, outp + (size_t)b * 524288);
    }
}

// Round 3
// 1117.077 us; speedup vs baseline: 1.3194x; 1.3194x over previous
//
#include <hip/hip_runtime.h>

// ---------------------------------------------------------------------------
// DeepseekV4Compressor on MI355X (gfx950) — round 2 resubmit (r1 bench never ran)
// fp32 GEMM via split-bf16 (hi/lo), K' = 3*4096 = 12288.
// GEMM: 256x256 tile, BK=64, 8 waves, 8-phase interleave, counted vmcnt,
// T2 LDS XOR-swizzle (pre-swizzled global source + swizzled ds_read),
// T5 setprio around MFMA, split-K=2 for full-chip occupancy.
// W rows interleaved (16 kv | 16 gate per 32-group) so gating pairs by n-frag.
// ---------------------------------------------------------------------------

typedef __attribute__((ext_vector_type(8))) __bf16 bf16x8;
typedef __attribute__((ext_vector_type(4))) float f32x4;

__device__ __forceinline__ void gld16(const void* g, void* l) {
    __builtin_amdgcn_global_load_lds(
        (const __attribute__((address_space(1))) void*)g,
        (__attribute__((address_space(3))) void*)l, 16, 0, 0);
}
__device__ __forceinline__ unsigned short bf16rn(float f) {
    unsigned int u = __float_as_uint(f);
    u += 0x7FFF + ((u >> 16) & 1);
    return (unsigned short)(u >> 16);
}
__device__ __forceinline__ float bf16tof(unsigned short h) {
    return __uint_as_float(((unsigned int)h) << 16);
}

// ---- convert x (one batch 4096x4096 f32) -> hi/lo bf16 --------------------
__global__ void convert_x_kernel(const float4* __restrict__ src,
                                 ushort4* __restrict__ hi,
                                 ushort4* __restrict__ lo) {
    const int i = blockIdx.x * 256 + threadIdx.x;
    const float4 v = src[i];
    ushort4 h, l;
    h.x = bf16rn(v.x); l.x = bf16rn(v.x - bf16tof(h.x));
    h.y = bf16rn(v.y); l.y = bf16rn(v.y - bf16tof(h.y));
    h.z = bf16rn(v.z); l.z = bf16rn(v.z - bf16tof(h.z));
    h.w = bf16rn(v.w); l.w = bf16rn(v.w - bf16tof(h.w));
    hi[i] = h; lo[i] = l;
}

// ---- W'' interleaved: row r: g=r>>5, wi=r&31; wi<16 -> kv[g*16+wi], else gate
__global__ void convert_w_kernel(const float* __restrict__ Wkv,
                                 const float* __restrict__ Wgate,
                                 ushort4* __restrict__ hi,
                                 ushort4* __restrict__ lo) {
    const int i = blockIdx.x * 256 + threadIdx.x;   // 2,097,152 float4s
    const size_t e = (size_t)i * 4;
    const int r = (int)(e >> 12);                   // W'' row 0..2047
    const int col = (int)(e & 4095);
    const int grp = r >> 5, wi = r & 31;
    const int srow = grp * 16 + (wi & 15);
    const float* srcrow = (wi < 16) ? (Wkv + ((size_t)srow << 12))
                                    : (Wgate + ((size_t)srow << 12));
    const float4 v = *(const float4*)(srcrow + col);
    ushort4 h, l;
    h.x = bf16rn(v.x); l.x = bf16rn(v.x - bf16tof(h.x));
    h.y = bf16rn(v.y); l.y = bf16rn(v.y - bf16tof(h.y));
    h.z = bf16rn(v.z); l.z = bf16rn(v.z - bf16tof(h.z));
    h.w = bf16rn(v.w); l.w = bf16rn(v.w - bf16tof(h.w));
    hi[i] = h; lo[i] = l;
}

// ---- softmax of ape -------------------------------------------------------
__global__ void softmax_kernel(const float* __restrict__ ape,
                               float* __restrict__ w8,
                               float* __restrict__ w0) {
    const int d = threadIdx.x;   // 512
    float v[8];
#pragma unroll
    for (int r = 0; r < 4; ++r) v[r] = ape[r * 1024 + d];
#pragma unroll
    for (int r = 0; r < 4; ++r) v[4 + r] = ape[r * 1024 + 512 + d];
    float mx = v[0];
#pragma unroll
    for (int i = 1; i < 8; ++i) mx = fmaxf(mx, v[i]);
    float e[8], s = 0.f;
#pragma unroll
    for (int i = 0; i < 8; ++i) { e[i] = expf(v[i] - mx); s += e[i]; }
    const float inv = 1.f / s;
#pragma unroll
    for (int i = 0; i < 8; ++i) w8[i * 512 + d] = e[i] * inv;
    float mx4 = fmaxf(fmaxf(v[0], v[1]), fmaxf(v[2], v[3]));
    float e4[4], s4 = 0.f;
#pragma unroll
    for (int i = 0; i < 4; ++i) { e4[i] = expf(v[i] - mx4); s4 += e4[i]; }
    const float inv4 = 1.f / s4;
#pragma unroll
    for (int i = 0; i < 4; ++i) w0[i * 512 + d] = e4[i] * inv4;
}

// ---- 8-phase 256^2 split-bf16 GEMM, split-K=2 -----------------------------
#define BAR() __builtin_amdgcn_s_barrier()
#define WAIT_LGKM0() asm volatile("s_waitcnt lgkmcnt(0)" ::: "memory")
#define WAIT_VM(n) asm volatile("s_waitcnt vmcnt(" #n ")" ::: "memory")

#define STAGE(g, h, bu) do {                                                   \
    const int seg_ = (g) >> 6;                                                 \
    const size_t kc_ = (size_t)(((g) & 63) * 64);                              \
    const unsigned short* bp_; size_t b0_, b1_; unsigned int lb_;              \
    if ((h) < 2) { bp_ = (seg_ == 1) ? Xlo : Xhi; b0_ = baseA0; b1_ = baseA1; lb_ = 0u; } \
    else         { bp_ = (seg_ == 2) ? Wlo : Whi; b0_ = baseB0; b1_ = baseB1; lb_ = 32768u; } \
    const size_t hof_ = ((h) & 1) ? (size_t)524288 : 0;  /* 128 rows * 4096 */ \
    const unsigned int ld_ = (unsigned)(bu) * 65536u + lb_ + (((h) & 1) ? 16384u : 0u); \
    gld16(bp_ + b0_ + hof_ + kc_, lds + ld_ + off0);                           \
    gld16(bp_ + b1_ + hof_ + kc_, lds + ld_ + off1);                           \
} while (0)

#define LDA(bu, mh) do {                                                       \
    const char* p_ = aRow + (bu) * 65536u + (mh) * 8192u;                      \
    _Pragma("unroll") for (int mi = 0; mi < 4; ++mi) {                         \
        ra[mi][0] = *(const bf16x8*)(p_ + mi * 2048 + koff0);                  \
        ra[mi][1] = *(const bf16x8*)(p_ + mi * 2048 + (koff0 ^ 64)); }         \
} while (0)

#define LDB(bu, nh, rb) do {                                                   \
    const char* p_ = bRow + (bu) * 65536u + (nh) * 4096u;                      \
    _Pragma("unroll") for (int ni = 0; ni < 2; ++ni) {                         \
        rb[ni][0] = *(const bf16x8*)(p_ + ni * 2048 + koff0);                  \
        rb[ni][1] = *(const bf16x8*)(p_ + ni * 2048 + (koff0 ^ 64)); }         \
} while (0)

#define MM(mh, nh, rb) do {                                                    \
    __builtin_amdgcn_s_setprio(1);                                             \
    _Pragma("unroll") for (int mi = 0; mi < 4; ++mi)                           \
    _Pragma("unroll") for (int ni = 0; ni < 2; ++ni)                           \
    _Pragma("unroll") for (int kk = 0; kk < 2; ++kk)                           \
        acc[(mh) * 4 + mi][(nh) * 2 + ni] =                                    \
            __builtin_amdgcn_mfma_f32_16x16x32_bf16(                           \
                ra[mi][kk], rb[ni][kk], acc[(mh) * 4 + mi][(nh) * 2 + ni], 0, 0, 0); \
    __builtin_amdgcn_s_setprio(0);                                             \
} while (0)

template <int SPLITBUF>
__global__ __launch_bounds__(512, 2) void gemm8_kernel(
    const unsigned short* __restrict__ Xhi, const unsigned short* __restrict__ Xlo,
    const unsigned short* __restrict__ Whi, const unsigned short* __restrict__ Wlo,
    float* __restrict__ C) {
    extern __shared__ char lds[];   // 131072 B: [buf][A 32K | B 32K]
    const int t = threadIdx.x;
    const int lane = t & 63;
    const int w = t >> 6;
    const int wm = (w >> 2) * 128;
    const int wn = (w & 3) * 64;

    // XCD chunking: each XCD gets 32 consecutive sw
    const int sw = (blockIdx.x & 7) * 32 + (blockIdx.x >> 3);
    const int z = sw & 1;
    const int bn = (sw >> 1) & 7;
    const int bm = sw >> 4;

    // staging source precompute (2 issues of 16B per STAGE)
    const unsigned int off0 = t * 16u;            // byte in 16KB half-tile
    const unsigned int off1 = off0 + 8192u;
    const unsigned int r0 = off0 >> 7, r1 = off1 >> 7;
    const unsigned int sc0 = ((off0 >> 4) & 7) ^ (r0 & 7);   // inverse swizzle
    const unsigned int sc1 = ((off1 >> 4) & 7) ^ (r1 & 7);
    const size_t baseA0 = (size_t)(bm * 256 + r0) * 4096 + sc0 * 8;
    const size_t baseA1 = (size_t)(bm * 256 + r1) * 4096 + sc1 * 8;
    const size_t baseB0 = (size_t)(bn * 256 + r0) * 4096 + sc0 * 8;
    const size_t baseB1 = (size_t)(bn * 256 + r1) * 4096 + sc1 * 8;

    // fragment-read bases (swizzled): row&7 == lane&7 for all frag rows
    const unsigned int koff0 = (((lane >> 4) * 16u) ^ ((lane & 7) << 4));
    const char* aRow = lds + (unsigned)(wm + (lane & 15)) * 128u;
    const char* bRow = lds + 32768u + (unsigned)(wn + (lane & 15)) * 128u;

    f32x4 acc[8][4];
    const f32x4 zero = {0.f, 0.f, 0.f, 0.f};
#pragma unroll
    for (int mi = 0; mi < 8; ++mi)
#pragma unroll
        for (int nj = 0; nj < 4; ++nj) acc[mi][nj] = zero;

    bf16x8 ra[4][2], rb0[2][2], rb1[2][2];

    const int g00 = z * 96;          // 96 K-tiles per split-K part
    // prologue: tile g00 fully into buf0, tile g00+1 half A0 into buf1
    STAGE(g00, 0, 0); STAGE(g00, 1, 0); STAGE(g00, 2, 0); STAGE(g00, 3, 0);
    STAGE(g00 + 1, 0, 1);
    WAIT_VM(2); BAR();

    for (int i = 0; i < 48; ++i) {
        const int ga = g00 + 2 * i;
        const int gb = ga + 1;
        const bool nl = (i < 47);
        // P0: read A0,B0 (buf0); stage gb.A1 -> buf1
        LDA(0, 0); LDB(0, 0, rb0);
        STAGE(gb, 1, 1);
        BAR(); WAIT_LGKM0();
        MM(0, 0, rb0);
        BAR();
        // P1: read B1 (buf0); stage gb.B0 -> buf1
        LDB(0, 1, rb1);
        STAGE(gb, 2, 1);
        BAR(); WAIT_LGKM0();
        MM(0, 1, rb1);
        BAR();
        // P2: read A1 (buf0); stage gb.B1 -> buf1
        LDA(0, 1);
        STAGE(gb, 3, 1);
        BAR(); WAIT_LGKM0();
        MM(1, 1, rb1);
        BAR();
        // P3: stage (ga+2).A0 -> buf0; MFMA; buf1 complete after this
        if (nl) { STAGE(ga + 2, 0, 0); }
        MM(1, 0, rb0);
        if (nl) { WAIT_VM(2); } else { WAIT_VM(0); }
        BAR();
        // P4: read A0,B0 (buf1); stage (ga+2).A1 -> buf0
        LDA(1, 0); LDB(1, 0, rb0);
        if (nl) { STAGE(ga + 2, 1, 0); }
        BAR(); WAIT_LGKM0();
        MM(0, 0, rb0);
        BAR();
        // P5: read B1 (buf1); stage (ga+2).B0 -> buf0
        LDB(1, 1, rb1);
        if (nl) { STAGE(ga + 2, 2, 0); }
        BAR(); WAIT_LGKM0();
        MM(0, 1, rb1);
        BAR();
        // P6: read A1 (buf1); stage (ga+2).B1 -> buf0
        LDA(1, 1);
        if (nl) { STAGE(ga + 2, 3, 0); }
        BAR(); WAIT_LGKM0();
        MM(1, 1, rb1);
        BAR();
        // P7: stage (ga+3).A0 -> buf1; MFMA; buf0 complete after this
        if (nl) {
            STAGE(ga + 3, 0, 1);
            MM(1, 0, rb0);
            WAIT_VM(2); BAR();
        } else {
            MM(1, 0, rb0);
        }
    }

    // epilogue: C/D layout col=lane&15, row=(lane>>4)*4+ii
    const int c0 = bn * 256 + wn + (lane & 15);
    const int r0e = bm * 256 + wm + (lane >> 4) * 4;
    if (SPLITBUF) {
        float* Co = C + (size_t)z * 8388608;
#pragma unroll
        for (int mi = 0; mi < 8; ++mi)
#pragma unroll
            for (int nj = 0; nj < 4; ++nj) {
                float* cp = Co + (size_t)(r0e + mi * 16) * 2048 + (c0 + nj * 16);
#pragma unroll
                for (int ii = 0; ii < 4; ++ii) cp[(size_t)ii * 2048] = acc[mi][nj][ii];
            }
    } else {
#pragma unroll
        for (int mi = 0; mi < 8; ++mi)
#pragma unroll
            for (int nj = 0; nj < 4; ++nj) {
                float* cp = C + (size_t)(r0e + mi * 16) * 2048 + (c0 + nj * 16);
#pragma unroll
                for (int ii = 0; ii < 4; ++ii) atomicAdd(cp + (size_t)ii * 2048, acc[mi][nj][ii]);
            }
    }
}

// ---- fused split-K reduce + gate + combine + RMS + RoPE -------------------
template <int SPLIT>
__global__ void combine2_kernel(const float* __restrict__ C0,
                                const float* __restrict__ w8,
                                const float* __restrict__ w0,
                                const float* __restrict__ cosb,
                                const float* __restrict__ sinb,
                                const float* __restrict__ normw,
                                float* __restrict__ outb) {
    const int c = blockIdx.x;      // 0..1023
    const int t = threadIdx.x;     // 0..255
    const int d = t * 2;           // main dim pair
    const int jm = ((d >> 4) * 32) + (d & 15);   // kv col (gate at +16)
    float o0 = 0.f, o1 = 0.f;

    const float* rowp = C0 + (size_t)c * (4 * 2048);
    const float* wsel = (c == 0) ? w0 : w8;
#pragma unroll
    for (int r = 0; r < 4; ++r) {
        const float* rp = rowp + r * 2048;
        float2 kv = *(const float2*)(rp + jm);
        float2 gt = *(const float2*)(rp + jm + 16);
        if (SPLIT) {
            const float2 kv1 = *(const float2*)(rp + 8388608 + jm);
            const float2 gt1 = *(const float2*)(rp + 8388608 + jm + 16);
            kv.x += kv1.x; kv.y += kv1.y; gt.x += gt1.x; gt.y += gt1.y;
        }
        o0 += (kv.x / (1.f + expf(-gt.x))) * wsel[r * 512 + d];
        o1 += (kv.y / (1.f + expf(-gt.y))) * wsel[r * 512 + d + 1];
    }
    if (c > 0) {
        const float* prow = C0 + (size_t)(c - 1) * (4 * 2048) + 1024;  // ov cols
#pragma unroll
        for (int r = 0; r < 4; ++r) {
            const float* rp = prow + r * 2048;
            float2 kv = *(const float2*)(rp + jm);
            float2 gt = *(const float2*)(rp + jm + 16);
            if (SPLIT) {
                const float2 kv1 = *(const float2*)(rp + 8388608 + jm);
                const float2 gt1 = *(const float2*)(rp + 8388608 + jm + 16);
                kv.x += kv1.x; kv.y += kv1.y; gt.x += gt1.x; gt.y += gt1.y;
            }
            o0 += (kv.x / (1.f + expf(-gt.x))) * w8[(4 + r) * 512 + d];
            o1 += (kv.y / (1.f + expf(-gt.y))) * w8[(4 + r) * 512 + d + 1];
        }
    }

    // RMS over 512
    float p = o0 * o0 + o1 * o1;
#pragma unroll
    for (int off = 32; off > 0; off >>= 1) p += __shfl_down(p, off, 64);
    __shared__ float red[4];
    if ((t & 63) == 0) red[t >> 6] = p;
    __syncthreads();
    const float sc = rsqrtf((red[0] + red[1] + red[2] + red[3]) * (1.f / 512.f) + 1e-6f);
    o0 *= sc * normw[d];
    o1 *= sc * normw[d + 1];

    float2 res;
    if (d < 448) {
        res.x = o0; res.y = o1;
    } else {
        const int j = (d - 448) >> 1;
        const float cv = cosb[c * 32 + j];
        const float sv = sinb[c * 32 + j];
        res.x = o0 * cv - o1 * sv;
        res.y = o0 * sv + o1 * cv;
    }
    *(float2*)(outb + (size_t)c * 512 + d) = res;
}

// ---------------------------------------------------------------------------
extern "C" void kernel_launch(void* const* d_in, const int* in_sizes, int n_in,
                              void* d_out, int out_size, void* d_ws, size_t ws_size,
                              hipStream_t stream) {
    const float* x     = (const float*)d_in[0];
    const float* cosp  = (const float*)d_in[1];
    const float* sinp  = (const float*)d_in[2];
    const float* Wkv   = (const float*)d_in[3];
    const float* Wgate = (const float*)d_in[4];
    const float* ape   = (const float*)d_in[5];
    const float* normw = (const float*)d_in[6];
    float* outp = (float*)d_out;

    char* wsb = (char*)d_ws;
    const size_t MB = 1024 * 1024;
    unsigned short* Xhi = (unsigned short*)(wsb);             // 32MB
    unsigned short* Xlo = (unsigned short*)(wsb + 32 * MB);   // 32MB
    unsigned short* Whi = (unsigned short*)(wsb + 64 * MB);   // 16MB
    unsigned short* Wlo = (unsigned short*)(wsb + 80 * MB);   // 16MB
    float* Cz = (float*)(wsb + 96 * MB);                      // 32MB (64MB if split)

    const bool split = (ws_size >= 160 * MB + 32768);
    char* tail = wsb + (split ? 160 * MB : 128 * MB);
    float* W8 = (float*)tail;
    float* W0 = (float*)(tail + 16384);

    (void)hipFuncSetAttribute((const void*)gemm8_kernel<1>,
                              hipFuncAttributeMaxDynamicSharedMemorySize, 131072);
    (void)hipFuncSetAttribute((const void*)gemm8_kernel<0>,
                              hipFuncAttributeMaxDynamicSharedMemorySize, 131072);

    convert_w_kernel<<<8192, 256, 0, stream>>>(Wkv, Wgate, (ushort4*)Whi, (ushort4*)Wlo);
    softmax_kernel<<<1, 512, 0, stream>>>(ape, W8, W0);

    for (int b = 0; b < 4; ++b) {
        convert_x_kernel<<<16384, 256, 0, stream>>>(
            (const float4*)(x + (size_t)b * 16777216), (ushort4*)Xhi, (ushort4*)Xlo);
        if (split) {
            gemm8_kernel<1><<<256, 512, 131072, stream>>>(Xhi, Xlo, Whi, Wlo, Cz);
            combine2_kernel<1><<<1024, 256, 0, stream>>>(
                Cz, W8, W0, cosp + (size_t)b * 32768, sinp + (size_t)b * 32768,
                normw, outp + (size_t)b * 524288);
        } else {
            hipMemsetAsync(Cz, 0, 32 * MB, stream);
            gemm8_kernel<0><<<256, 512, 131072, stream>>>(Xhi, Xlo, Whi, Wlo, Cz);
            combine2_kernel<0><<<1024, 256, 0, stream>>>(
                Cz, W8, W0, cosp + (size_t)b * 32768, sinp + (size_t)b * 32768,
                normw, outp + (size_t)b * 524288);
        }
    }
}

// Round 5
// 1109.109 us; speedup vs baseline: 1.3289x; 1.0072x over previous
//
#include <hip/hip_runtime.h>

// ---------------------------------------------------------------------------
// DeepseekV4Compressor on MI355X (gfx950) — round 5
// fp32 GEMM via split-bf16 (hi/lo), K' = 3*4096 = 12288.
// GEMM: 256x256 tile, BK=64, 8 waves, 8-phase interleave, T2 swizzle,
// T5 setprio, split-K=2, EAGER STAGING (corrected): B-halves of next tile
// staged at P2/P6 (after B's last reader P1/P5), A-halves at P3/P7 (after
// A's last reader P2/P6). Every load gets 5-6 phases to land; WAIT_VM(8)
// counted, never drained below 8 in steady state.
// Region->last-reader map (per buf): A.h0/h1 last read at P2 (LDA mh=1),
// B.h2/h3 last read at P1 (LDB nh=1). Restage >=1 barrier later only.
// ---------------------------------------------------------------------------

typedef __attribute__((ext_vector_type(8))) __bf16 bf16x8;
typedef __attribute__((ext_vector_type(4))) float f32x4;
typedef __attribute__((ext_vector_type(8))) unsigned short u16x8;

__device__ __forceinline__ void gld16(const void* g, void* l) {
    __builtin_amdgcn_global_load_lds(
        (const __attribute__((address_space(1))) void*)g,
        (__attribute__((address_space(3))) void*)l, 16, 0, 0);
}
__device__ __forceinline__ unsigned short bf16rn(float f) {
    unsigned int u = __float_as_uint(f);
    u += 0x7FFF + ((u >> 16) & 1);
    return (unsigned short)(u >> 16);
}
__device__ __forceinline__ float bf16tof(unsigned short h) {
    return __uint_as_float(((unsigned int)h) << 16);
}

// ---- convert x (one batch 4096x4096 f32) -> hi/lo bf16, 8 elems/thread ----
__global__ void convert_x_kernel(const float* __restrict__ src,
                                 unsigned short* __restrict__ hi,
                                 unsigned short* __restrict__ lo) {
    const size_t i = ((size_t)blockIdx.x * 256 + threadIdx.x) * 8;
    const float4 v0 = *(const float4*)(src + i);
    const float4 v1 = *(const float4*)(src + i + 4);
    float v[8] = {v0.x, v0.y, v0.z, v0.w, v1.x, v1.y, v1.z, v1.w};
    u16x8 h, l;
#pragma unroll
    for (int j = 0; j < 8; ++j) {
        h[j] = bf16rn(v[j]);
        l[j] = bf16rn(v[j] - bf16tof(h[j]));
    }
    *(u16x8*)(hi + i) = h;
    *(u16x8*)(lo + i) = l;
}

// ---- W'' interleaved: row r: g=r>>5, wi=r&31; wi<16 -> kv[g*16+wi], else gate
__global__ void convert_w_kernel(const float* __restrict__ Wkv,
                                 const float* __restrict__ Wgate,
                                 unsigned short* __restrict__ hi,
                                 unsigned short* __restrict__ lo) {
    const size_t i = ((size_t)blockIdx.x * 256 + threadIdx.x) * 8;  // 1M groups
    const int r = (int)(i >> 12);                   // W'' row 0..2047
    const int col = (int)(i & 4095);
    const int grp = r >> 5, wi = r & 31;
    const int srow = grp * 16 + (wi & 15);
    const float* srcrow = (wi < 16) ? (Wkv + ((size_t)srow << 12))
                                    : (Wgate + ((size_t)srow << 12));
    const float4 v0 = *(const float4*)(srcrow + col);
    const float4 v1 = *(const float4*)(srcrow + col + 4);
    float v[8] = {v0.x, v0.y, v0.z, v0.w, v1.x, v1.y, v1.z, v1.w};
    u16x8 h, l;
#pragma unroll
    for (int j = 0; j < 8; ++j) {
        h[j] = bf16rn(v[j]);
        l[j] = bf16rn(v[j] - bf16tof(h[j]));
    }
    *(u16x8*)(hi + i) = h;
    *(u16x8*)(lo + i) = l;
}

// ---- softmax of ape -------------------------------------------------------
__global__ void softmax_kernel(const float* __restrict__ ape,
                               float* __restrict__ w8,
                               float* __restrict__ w0) {
    const int d = threadIdx.x;   // 512
    float v[8];
#pragma unroll
    for (int r = 0; r < 4; ++r) v[r] = ape[r * 1024 + d];
#pragma unroll
    for (int r = 0; r < 4; ++r) v[4 + r] = ape[r * 1024 + 512 + d];
    float mx = v[0];
#pragma unroll
    for (int i = 1; i < 8; ++i) mx = fmaxf(mx, v[i]);
    float e[8], s = 0.f;
#pragma unroll
    for (int i = 0; i < 8; ++i) { e[i] = expf(v[i] - mx); s += e[i]; }
    const float inv = 1.f / s;
#pragma unroll
    for (int i = 0; i < 8; ++i) w8[i * 512 + d] = e[i] * inv;
    float mx4 = fmaxf(fmaxf(v[0], v[1]), fmaxf(v[2], v[3]));
    float e4[4], s4 = 0.f;
#pragma unroll
    for (int i = 0; i < 4; ++i) { e4[i] = expf(v[i] - mx4); s4 += e4[i]; }
    const float inv4 = 1.f / s4;
#pragma unroll
    for (int i = 0; i < 4; ++i) w0[i * 512 + d] = e4[i] * inv4;
}

// ---- 8-phase 256^2 split-bf16 GEMM, split-K=2, eager staging --------------
#define BAR() __builtin_amdgcn_s_barrier()
#define WAIT_LGKM0() asm volatile("s_waitcnt lgkmcnt(0)" ::: "memory")
#define WAIT_VM(n) asm volatile("s_waitcnt vmcnt(" #n ")" ::: "memory")

// half-tiles: h=0 A rows0-127, h=1 A rows128-255, h=2 B rows0-127, h=3 B rows128-255
#define STAGE(g, h, bu) do {                                                   \
    const int seg_ = (g) >> 6;                                                 \
    const size_t kc_ = (size_t)(((g) & 63) * 64);                              \
    const unsigned short* bp_; size_t b0_, b1_; unsigned int lb_;              \
    if ((h) < 2) { bp_ = (seg_ == 1) ? Xlo : Xhi; b0_ = baseA0; b1_ = baseA1; lb_ = 0u; } \
    else         { bp_ = (seg_ == 2) ? Wlo : Whi; b0_ = baseB0; b1_ = baseB1; lb_ = 32768u; } \
    const size_t hof_ = ((h) & 1) ? (size_t)524288 : 0;  /* 128 rows * 4096 */ \
    const unsigned int ld_ = (unsigned)(bu) * 65536u + lb_ + (((h) & 1) ? 16384u : 0u); \
    gld16(bp_ + b0_ + hof_ + kc_, lds + ld_ + off0);                           \
    gld16(bp_ + b1_ + hof_ + kc_, lds + ld_ + off1);                           \
} while (0)

#define LDA(bu, mh) do {                                                       \
    const char* p_ = aRow + (bu) * 65536u + (mh) * 8192u;                      \
    _Pragma("unroll") for (int mi = 0; mi < 4; ++mi) {                         \
        ra[mi][0] = *(const bf16x8*)(p_ + mi * 2048 + koff0);                  \
        ra[mi][1] = *(const bf16x8*)(p_ + mi * 2048 + (koff0 ^ 64)); }         \
} while (0)

#define LDB(bu, nh, rb) do {                                                   \
    const char* p_ = bRow + (bu) * 65536u + (nh) * 4096u;                      \
    _Pragma("unroll") for (int ni = 0; ni < 2; ++ni) {                         \
        rb[ni][0] = *(const bf16x8*)(p_ + ni * 2048 + koff0);                  \
        rb[ni][1] = *(const bf16x8*)(p_ + ni * 2048 + (koff0 ^ 64)); }         \
} while (0)

#define MM(mh, nh, rb) do {                                                    \
    __builtin_amdgcn_s_setprio(1);                                             \
    _Pragma("unroll") for (int mi = 0; mi < 4; ++mi)                           \
    _Pragma("unroll") for (int ni = 0; ni < 2; ++ni)                           \
    _Pragma("unroll") for (int kk = 0; kk < 2; ++kk)                           \
        acc[(mh) * 4 + mi][(nh) * 2 + ni] =                                    \
            __builtin_amdgcn_mfma_f32_16x16x32_bf16(                           \
                ra[mi][kk], rb[ni][kk], acc[(mh) * 4 + mi][(nh) * 2 + ni], 0, 0, 0); \
    __builtin_amdgcn_s_setprio(0);                                             \
} while (0)

template <int SPLITBUF>
__global__ __launch_bounds__(512, 2) void gemm8_kernel(
    const unsigned short* __restrict__ Xhi, const unsigned short* __restrict__ Xlo,
    const unsigned short* __restrict__ Whi, const unsigned short* __restrict__ Wlo,
    float* __restrict__ C) {
    extern __shared__ char lds[];   // 131072 B: [buf][A 32K | B 32K]
    const int t = threadIdx.x;
    const int lane = t & 63;
    const int w = t >> 6;
    const int wm = (w >> 2) * 128;
    const int wn = (w & 3) * 64;

    // XCD chunking: each XCD gets 32 consecutive sw
    const int sw = (blockIdx.x & 7) * 32 + (blockIdx.x >> 3);
    const int z = sw & 1;
    const int bn = (sw >> 1) & 7;
    const int bm = sw >> 4;

    // staging source precompute (2 issues of 16B per STAGE)
    const unsigned int off0 = t * 16u;            // byte in 16KB half-tile
    const unsigned int off1 = off0 + 8192u;
    const unsigned int r0 = off0 >> 7, r1 = off1 >> 7;
    const unsigned int sc0 = ((off0 >> 4) & 7) ^ (r0 & 7);   // inverse swizzle
    const unsigned int sc1 = ((off1 >> 4) & 7) ^ (r1 & 7);
    const size_t baseA0 = (size_t)(bm * 256 + r0) * 4096 + sc0 * 8;
    const size_t baseA1 = (size_t)(bm * 256 + r1) * 4096 + sc1 * 8;
    const size_t baseB0 = (size_t)(bn * 256 + r0) * 4096 + sc0 * 8;
    const size_t baseB1 = (size_t)(bn * 256 + r1) * 4096 + sc1 * 8;

    // fragment-read bases (swizzled): row&7 == lane&7 for all frag rows
    const unsigned int koff0 = (((lane >> 4) * 16u) ^ ((lane & 7) << 4));
    const char* aRow = lds + (unsigned)(wm + (lane & 15)) * 128u;
    const char* bRow = lds + 32768u + (unsigned)(wn + (lane & 15)) * 128u;

    f32x4 acc[8][4];
    const f32x4 zero = {0.f, 0.f, 0.f, 0.f};
#pragma unroll
    for (int mi = 0; mi < 8; ++mi)
#pragma unroll
        for (int nj = 0; nj < 4; ++nj) acc[mi][nj] = zero;

    bf16x8 ra[4][2], rb0[2][2], rb1[2][2];

    const int g00 = z * 96;          // 96 K-tiles per split-K part
    // prologue: tile g00 -> buf0 (8 loads), tile g00+1 -> buf1 (8 loads)
    STAGE(g00, 0, 0); STAGE(g00, 1, 0); STAGE(g00, 2, 0); STAGE(g00, 3, 0);
    STAGE(g00 + 1, 0, 1); STAGE(g00 + 1, 1, 1); STAGE(g00 + 1, 2, 1); STAGE(g00 + 1, 3, 1);
    WAIT_VM(8); BAR();   // g00 landed; g00+1's 8 still in flight

    for (int i = 0; i < 48; ++i) {
        const int ga = g00 + 2 * i;
        const bool nl = (i < 47);
        // P0: read buf0 A-half0, B-half0
        LDA(0, 0); LDB(0, 0, rb0);
        BAR(); WAIT_LGKM0();
        MM(0, 0, rb0);
        BAR();
        // P1: read buf0 B-half1 (last B reader of buf0)
        LDB(0, 1, rb1);
        BAR(); WAIT_LGKM0();
        MM(0, 1, rb1);
        BAR();
        // P2: B regions of buf0 free -> stage (ga+2).B; read buf0 A-half1 (last A reader)
        if (nl) { STAGE(ga + 2, 2, 0); STAGE(ga + 2, 3, 0); }
        LDA(0, 1);
        BAR(); WAIT_LGKM0();
        MM(1, 1, rb1);
        BAR();
        // P3: A regions of buf0 free -> stage (ga+2).A; MM; wait (ga+1)'s 8 landed
        if (nl) { STAGE(ga + 2, 0, 0); STAGE(ga + 2, 1, 0); }
        MM(1, 0, rb0);
        if (nl) { WAIT_VM(8); } else { WAIT_VM(0); }
        BAR();
        // P4: read buf1 A-half0, B-half0
        LDA(1, 0); LDB(1, 0, rb0);
        BAR(); WAIT_LGKM0();
        MM(0, 0, rb0);
        BAR();
        // P5: read buf1 B-half1 (last B reader of buf1)
        LDB(1, 1, rb1);
        BAR(); WAIT_LGKM0();
        MM(0, 1, rb1);
        BAR();
        // P6: B regions of buf1 free -> stage (ga+3).B; read buf1 A-half1 (last A reader)
        if (nl) { STAGE(ga + 3, 2, 1); STAGE(ga + 3, 3, 1); }
        LDA(1, 1);
        BAR(); WAIT_LGKM0();
        MM(1, 1, rb1);
        BAR();
        // P7: A regions of buf1 free -> stage (ga+3).A; MM; wait (ga+2)'s 8 landed
        if (nl) {
            STAGE(ga + 3, 0, 1); STAGE(ga + 3, 1, 1);
            MM(1, 0, rb0);
            WAIT_VM(8); BAR();
        } else {
            MM(1, 0, rb0);
        }
    }

    // epilogue: C/D layout col=lane&15, row=(lane>>4)*4+ii
    const int c0 = bn * 256 + wn + (lane & 15);
    const int r0e = bm * 256 + wm + (lane >> 4) * 4;
    if (SPLITBUF) {
        float* Co = C + (size_t)z * 8388608;
#pragma unroll
        for (int mi = 0; mi < 8; ++mi)
#pragma unroll
            for (int nj = 0; nj < 4; ++nj) {
                float* cp = Co + (size_t)(r0e + mi * 16) * 2048 + (c0 + nj * 16);
#pragma unroll
                for (int ii = 0; ii < 4; ++ii) cp[(size_t)ii * 2048] = acc[mi][nj][ii];
            }
    } else {
#pragma unroll
        for (int mi = 0; mi < 8; ++mi)
#pragma unroll
            for (int nj = 0; nj < 4; ++nj) {
                float* cp = C + (size_t)(r0e + mi * 16) * 2048 + (c0 + nj * 16);
#pragma unroll
                for (int ii = 0; ii < 4; ++ii) atomicAdd(cp + (size_t)ii * 2048, acc[mi][nj][ii]);
            }
    }
}

// ---- fused split-K reduce + gate + combine + RMS + RoPE -------------------
template <int SPLIT>
__global__ void combine2_kernel(const float* __restrict__ C0,
                                const float* __restrict__ w8,
                                const float* __restrict__ w0,
                                const float* __restrict__ cosb,
                                const float* __restrict__ sinb,
                                const float* __restrict__ normw,
                                float* __restrict__ outb) {
    const int c = blockIdx.x;      // 0..1023
    const int t = threadIdx.x;     // 0..255
    const int d = t * 2;           // main dim pair
    const int jm = ((d >> 4) * 32) + (d & 15);   // kv col (gate at +16)
    float o0 = 0.f, o1 = 0.f;

    const float* rowp = C0 + (size_t)c * (4 * 2048);
    const float* wsel = (c == 0) ? w0 : w8;
#pragma unroll
    for (int r = 0; r < 4; ++r) {
        const float* rp = rowp + r * 2048;
        float2 kv = *(const float2*)(rp + jm);
        float2 gt = *(const float2*)(rp + jm + 16);
        if (SPLIT) {
            const float2 kv1 = *(const float2*)(rp + 8388608 + jm);
            const float2 gt1 = *(const float2*)(rp + 8388608 + jm + 16);
            kv.x += kv1.x; kv.y += kv1.y; gt.x += gt1.x; gt.y += gt1.y;
        }
        o0 += (kv.x / (1.f + expf(-gt.x))) * wsel[r * 512 + d];
        o1 += (kv.y / (1.f + expf(-gt.y))) * wsel[r * 512 + d + 1];
    }
    if (c > 0) {
        const float* prow = C0 + (size_t)(c - 1) * (4 * 2048) + 1024;  // ov cols
#pragma unroll
        for (int r = 0; r < 4; ++r) {
            const float* rp = prow + r * 2048;
            float2 kv = *(const float2*)(rp + jm);
            float2 gt = *(const float2*)(rp + jm + 16);
            if (SPLIT) {
                const float2 kv1 = *(const float2*)(rp + 8388608 + jm);
                const float2 gt1 = *(const float2*)(rp + 8388608 + jm + 16);
                kv.x += kv1.x; kv.y += kv1.y; gt.x += gt1.x; gt.y += gt1.y;
            }
            o0 += (kv.x / (1.f + expf(-gt.x))) * w8[(4 + r) * 512 + d];
            o1 += (kv.y / (1.f + expf(-gt.y))) * w8[(4 + r) * 512 + d + 1];
        }
    }

    // RMS over 512
    float p = o0 * o0 + o1 * o1;
#pragma unroll
    for (int off = 32; off > 0; off >>= 1) p += __shfl_down(p, off, 64);
    __shared__ float red[4];
    if ((t & 63) == 0) red[t >> 6] = p;
    __syncthreads();
    const float sc = rsqrtf((red[0] + red[1] + red[2] + red[3]) * (1.f / 512.f) + 1e-6f);
    o0 *= sc * normw[d];
    o1 *= sc * normw[d + 1];

    float2 res;
    if (d < 448) {
        res.x = o0; res.y = o1;
    } else {
        const int j = (d - 448) >> 1;
        const float cv = cosb[c * 32 + j];
        const float sv = sinb[c * 32 + j];
        res.x = o0 * cv - o1 * sv;
        res.y = o0 * sv + o1 * cv;
    }
    *(float2*)(outb + (size_t)c * 512 + d) = res;
}

// ---------------------------------------------------------------------------
extern "C" void kernel_launch(void* const* d_in, const int* in_sizes, int n_in,
                              void* d_out, int out_size, void* d_ws, size_t ws_size,
                              hipStream_t stream) {
    const float* x     = (const float*)d_in[0];
    const float* cosp  = (const float*)d_in[1];
    const float* sinp  = (const float*)d_in[2];
    const float* Wkv   = (const float*)d_in[3];
    const float* Wgate = (const float*)d_in[4];
    const float* ape   = (const float*)d_in[5];
    const float* normw = (const float*)d_in[6];
    float* outp = (float*)d_out;

    char* wsb = (char*)d_ws;
    const size_t MB = 1024 * 1024;
    unsigned short* Xhi = (unsigned short*)(wsb);             // 32MB
    unsigned short* Xlo = (unsigned short*)(wsb + 32 * MB);   // 32MB
    unsigned short* Whi = (unsigned short*)(wsb + 64 * MB);   // 16MB
    unsigned short* Wlo = (unsigned short*)(wsb + 80 * MB);   // 16MB
    float* Cz = (float*)(wsb + 96 * MB);                      // 32MB (64MB if split)

    const bool split = (ws_size >= 160 * MB + 32768);
    char* tail = wsb + (split ? 160 * MB : 128 * MB);
    float* W8 = (float*)tail;
    float* W0 = (float*)(tail + 16384);

    (void)hipFuncSetAttribute((const void*)gemm8_kernel<1>,
                              hipFuncAttributeMaxDynamicSharedMemorySize, 131072);
    (void)hipFuncSetAttribute((const void*)gemm8_kernel<0>,
                              hipFuncAttributeMaxDynamicSharedMemorySize, 131072);

    convert_w_kernel<<<4096, 256, 0, stream>>>(Wkv, Wgate, Whi, Wlo);
    softmax_kernel<<<1, 512, 0, stream>>>(ape, W8, W0);

    for (int b = 0; b < 4; ++b) {
        convert_x_kernel<<<8192, 256, 0, stream>>>(
            x + (size_t)b * 16777216, Xhi, Xlo);
        if (split) {
            gemm8_kernel<1><<<256, 512, 131072, stream>>>(Xhi, Xlo, Whi, Wlo, Cz);
            combine2_kernel<1><<<1024, 256, 0, stream>>>(
                Cz, W8, W0, cosp + (size_t)b * 32768, sinp + (size_t)b * 32768,
                normw, outp + (size_t)b * 524288);
        } else {
            hipMemsetAsync(Cz, 0, 32 * MB, stream);
            gemm8_kernel<0><<<256, 512, 131072, stream>>>(Xhi, Xlo, Whi, Wlo, Cz);
            combine2_kernel<0><<<1024, 256, 0, stream>>>(
                Cz, W8, W0, cosp + (size_t)b * 32768, sinp + (size_t)b * 32768,
                normw, outp + (size_t)b * 524288);
        }
    }
}